// Round 6
// baseline (2177.719 us; speedup 1.0000x reference)
//
#include <hip/hip_runtime.h>

#define NN 100000
#define NE 1000000
#define NG 100
#define DD 70
#define EL 55              // edges per slot in k_edge2
#define CHUNK (9 * EL)     // 495 edges per block
#define NPS 3              // nodes per slot in k_edge0
#define SCB 512

__device__ __forceinline__ float sigmoidf_(float x) { return 1.f / (1.f + expf(-x)); }

// ---------- generic skinny dense: out[i,f] = sum_k x[i,k]*W[k,f] + b[f] ----------
template <int K>
__global__ __launch_bounds__(640) void k_dense(const float* __restrict__ x,
                                               const float* __restrict__ W,
                                               const float* __restrict__ bias,
                                               float* __restrict__ out, int nrows) {
    __shared__ float sW[K * DD];
    __shared__ float sb[DD];
    __shared__ float sx[9 * K];
    int t = threadIdx.x;
    for (int idx = t; idx < K * DD; idx += 640) sW[idx] = W[idx];
    if (t < DD) sb[t] = bias[t];
    int r = t / DD, f = t - r * DD;
    int base = blockIdx.x * 36;
    for (int c = 0; c < 4; ++c) {
        int rb = base + c * 9;
        __syncthreads();
        for (int idx = t; idx < 9 * K; idx += 640) {
            int rr = idx / K, kk = idx - rr * K;
            int i = rb + rr;
            sx[idx] = (i < nrows) ? x[(long)i * K + kk] : 0.f;
        }
        __syncthreads();
        int i = rb + r;
        if (r < 9 && i < nrows) {
            float acc = sb[f];
            const float* xr = &sx[r * K];
#pragma unroll 14
            for (int k = 0; k < K; ++k) acc = fmaf(xr[k], sW[k * DD + f], acc);
            out[(long)i * DD + f] = acc;
        }
    }
}

// ---------- v1 = We @ Wc0 ; v2 = be @ Wc0 + bc0 ----------
__global__ void k_pre(const float* __restrict__ We, const float* __restrict__ be,
                      const float* __restrict__ Wg, const float* __restrict__ bg,
                      float* __restrict__ v1, float* __restrict__ v2) {
    int f = threadIdx.x;
    if (f < DD) {
        const float* W2 = Wg + 2 * DD * DD;  // layer0, proj C
        const float* b2 = bg + 2 * DD;
        float a = 0.f, c = 0.f;
        for (int k = 0; k < DD; ++k) {
            a = fmaf(We[k], W2[k * DD + f], a);
            c = fmaf(be[k], W2[k * DD + f], c);
        }
        v1[f] = a;
        v2[f] = c + b2[f];
    }
}

// ---------- CSR build: count / scan / fill ----------
__global__ void k_count(const int* __restrict__ dst, int* __restrict__ off) {
    int j = blockIdx.x * 256 + threadIdx.x;
    if (j < NE) atomicAdd(&off[dst[j]], 1);
}

__global__ void k_scan_a(int* __restrict__ off, int* __restrict__ part) {
    __shared__ int s[SCB];
    int t = threadIdx.x, i = blockIdx.x * SCB + t;
    int v = (i < NN) ? off[i] : 0;
    s[t] = v;
    __syncthreads();
    for (int d = 1; d < SCB; d <<= 1) {
        int x = (t >= d) ? s[t - d] : 0;
        __syncthreads();
        s[t] += x;
        __syncthreads();
    }
    if (i < NN) off[i] = s[t] - v;             // exclusive within block
    if (t == SCB - 1) part[blockIdx.x] = s[t]; // block total
}

__global__ void k_scan_b(int* __restrict__ part, int nb) {
    __shared__ int s[256];
    int t = threadIdx.x;
    int v = (t < nb) ? part[t] : 0;
    s[t] = v;
    __syncthreads();
    for (int d = 1; d < 256; d <<= 1) {
        int x = (t >= d) ? s[t - d] : 0;
        __syncthreads();
        s[t] += x;
        __syncthreads();
    }
    if (t < nb) part[t] = s[t] - v;            // exclusive block offsets
}

__global__ void k_scan_c(int* __restrict__ off, const int* __restrict__ part) {
    int i = blockIdx.x * SCB + threadIdx.x;
    if (i < NN) off[i] += part[blockIdx.x];
}

__global__ void k_fill(const int* __restrict__ src, const int* __restrict__ dst,
                       const float* __restrict__ ef, const float* __restrict__ sne,
                       int* __restrict__ off, int* __restrict__ src_s,
                       float* __restrict__ ef_s, float* __restrict__ sne_s) {
    int j = blockIdx.x * 256 + threadIdx.x;
    if (j < NE) {
        int d = dst[j];
        int pos = atomicAdd(&off[d], 1);  // off becomes shifted: off[n] = end(n)
        src_s[pos] = src[j];
        ef_s[pos] = ef[j];
        sne_s[pos] = sne[j];
    }
}

// ---------- layer-0 edge pass: node-centric, ZERO global atomics ----------
// slot = (block,9-row); each slot owns NPS consecutive nodes; off is shifted (end-offsets).
__global__ __launch_bounds__(640) void k_edge0(
    const float* __restrict__ ef_s, const float* __restrict__ sne_s,
    const int* __restrict__ src_s, const int* __restrict__ off,
    const float* __restrict__ PB, const float* __restrict__ PD,
    const float* __restrict__ PE, const float* __restrict__ v1,
    const float* __restrict__ v2, float* __restrict__ num,
    float* __restrict__ den, float* __restrict__ red) {
    int t = threadIdx.x;
    int r = t / DD, f = t - r * DD;
    bool act = (r < 9);
    float c1 = 0.f, c2 = 0.f;
    if (act) { c1 = v1[f]; c2 = v2[f]; }
    float acc_s = 0.f, acc_q = 0.f;
    int sid = blockIdx.x * 9 + r;
    int n0 = sid * NPS, n1 = n0 + NPS;
    if (n1 > NN) n1 = NN;
    if (act && n0 < NN) {
        int e = (n0 == 0) ? 0 : off[n0 - 1];
        for (int nn = n0; nn < n1; ++nn) {
            int e_end = off[nn];
            float pe = PE[(long)nn * DD + f];
            float na = 0.f, da = 0.f;
            for (; e < e_end; ++e) {
                int s = src_s[e];
                float efv = ef_s[e], snv = sne_s[e];
                float en = PD[(long)s * DD + f] + pe + efv * c1 + c2;
                float sg = sigmoidf_(en);
                na = fmaf(sg, PB[(long)s * DD + f], na);
                da += sg;
                float tv = en * snv;
                acc_s += tv;
                acc_q = fmaf(tv, tv, acc_q);
            }
            num[(long)nn * DD + f] = na;
            den[(long)nn * DD + f] = da;
        }
    }
    __shared__ float ss[DD], sq[DD];
    if (t < DD) { ss[t] = 0.f; sq[t] = 0.f; }
    __syncthreads();
    if (act) { atomicAdd(&ss[f], acc_s); atomicAdd(&sq[f], acc_q); }
    __syncthreads();
    if (t < DD) {
        atomicAdd(&red[t], ss[t]);
        atomicAdd(&red[DD + t], sq[t]);
    }
}

// ---------- layer-2 edge kernel: sorted edges, W2 column pinned in VGPRs ----------
__global__ __launch_bounds__(640, 2) void k_edge2(
    const float* __restrict__ ef_s, const float* __restrict__ sne_s,
    const int* __restrict__ src_s, const int* __restrict__ off,
    const float* __restrict__ PD0, const float* __restrict__ PE0,
    const float* __restrict__ PB2, const float* __restrict__ PD2,
    const float* __restrict__ PE2,
    const float* __restrict__ v1, const float* __restrict__ v2,
    const float* __restrict__ murs_e, const float* __restrict__ ge,
    const float* __restrict__ bbe, const float* __restrict__ We,
    const float* __restrict__ be,
    const float* __restrict__ WC2, const float* __restrict__ bC2,
    float* __restrict__ num, float* __restrict__ den) {
    __shared__ float se[9 * 72];  // padded rows, 16B-aligned
    int t = threadIdx.x;
    int r = t / DD, f = t - r * DD;
    bool act = (r < 9);
    // Unconditional load of this thread's W2 column (f < 70 for ALL threads),
    // pinned into VGPRs via opaque asm defs (compiler cannot rematerialize).
    float wcol[DD];
#pragma unroll
    for (int k = 0; k < DD; ++k) wcol[k] = WC2[k * DD + f];
#pragma unroll
    for (int k = 0; k < DD; ++k) asm volatile("" : "+v"(wcol[k]));
    float c_v1 = 0.f, c_v2 = 0.f, c_mu = 0.f, c_rs = 0.f, c_g = 0.f, c_b = 0.f,
          c_We = 0.f, c_be = 0.f, c_b2 = 0.f;
    if (act) {
        c_v1 = v1[f]; c_v2 = v2[f];
        c_mu = murs_e[f]; c_rs = murs_e[DD + f];
        c_g = ge[f]; c_b = bbe[f];
        c_We = We[f]; c_be = be[f];
        c_b2 = bC2[f];
    }
    int e_beg = blockIdx.x * CHUNK + r * EL;
    bool live = act && e_beg < NE;
    int n = 0;
    float pe0 = 0.f, pe2 = 0.f, accn = 0.f, accd = 0.f;
    if (live) {
        int lo = 0, hi = NN - 1;  // smallest n with off[n] > e_beg (off[n] = end(n))
        while (lo < hi) {
            int mid = (lo + hi) >> 1;
            if (off[mid] > e_beg) hi = mid; else lo = mid + 1;
        }
        n = lo;
        pe0 = PE0[(long)n * DD + f];
        pe2 = PE2[(long)n * DD + f];
    }
    int s = 0;
    for (int it = 0; it < EL; ++it) {
        int e = e_beg + it;
        bool ok = live && e < NE;
        if (ok) {
            if (e >= off[n]) {  // crossed into next dst run: flush
                unsafeAtomicAdd(&num[(long)n * DD + f], accn);
                unsafeAtomicAdd(&den[(long)n * DD + f], accd);
                accn = 0.f; accd = 0.f;
                do { ++n; } while (off[n] <= e);  // skip empty buckets
                pe0 = PE0[(long)n * DD + f];
                pe2 = PE2[(long)n * DD + f];
            }
            s = src_s[e];
            float efv = ef_s[e], snv = sne_s[e];
            // e1[e,f] = e0 + relu(bn_e((Dh0[s]+Eh0[d]+Ce0)*sne))
            float en0 = PD0[(long)s * DD + f] + pe0 + efv * c_v1 + c_v2;
            float tv = en0 * snv;
            float bnv = (tv - c_mu) * c_rs * c_g + c_b;
            float e0v = fmaf(efv, c_We, c_be);
            se[r * 72 + f] = e0v + fmaxf(bnv, 0.f);
        }
        __syncthreads();
        if (ok) {
            float acc = c_b2;
            const float4* er4 = (const float4*)&se[r * 72];
#pragma unroll
            for (int q = 0; q < 17; ++q) {
                float4 ev = er4[q];
                acc = fmaf(ev.x, wcol[4 * q + 0], acc);
                acc = fmaf(ev.y, wcol[4 * q + 1], acc);
                acc = fmaf(ev.z, wcol[4 * q + 2], acc);
                acc = fmaf(ev.w, wcol[4 * q + 3], acc);
            }
            acc = fmaf(se[r * 72 + 68], wcol[68], acc);
            acc = fmaf(se[r * 72 + 69], wcol[69], acc);
            float en = PD2[(long)s * DD + f] + pe2 + acc;
            float sg = sigmoidf_(en);
            accn = fmaf(sg, PB2[(long)s * DD + f], accn);
            accd += sg;
        }
        __syncthreads();
    }
    if (live) {
        unsafeAtomicAdd(&num[(long)n * DD + f], accn);
        unsafeAtomicAdd(&den[(long)n * DD + f], accd);
    }
}

// ---------- node BN stats: grid-stride, reg-accum ----------
__global__ __launch_bounds__(640) void k_nstats(const float* __restrict__ PA,
                                                const float* __restrict__ num,
                                                const float* __restrict__ den,
                                                const float* __restrict__ snn,
                                                float* __restrict__ red) {
    int t = threadIdx.x;
    int r = t / DD, f = t - r * DD;
    bool act = (r < 9);
    float acc_s = 0.f, acc_q = 0.f;
    const int T = (NN + 8) / 9;
    for (int tile = blockIdx.x; tile < T; tile += gridDim.x) {
        int i = tile * 9 + r;
        if (act && i < NN) {
            long o = (long)i * DD + f;
            float v = (PA[o] + num[o] / (den[o] + 1e-6f)) * snn[i];
            acc_s += v;
            acc_q = fmaf(v, v, acc_q);
        }
    }
    __shared__ float ss[DD], sq[DD];
    if (t < DD) { ss[t] = 0.f; sq[t] = 0.f; }
    __syncthreads();
    if (act) { atomicAdd(&ss[f], acc_s); atomicAdd(&sq[f], acc_q); }
    __syncthreads();
    if (t < DD) {
        atomicAdd(&red[t], ss[t]);
        atomicAdd(&red[DD + t], sq[t]);
    }
}

// ---------- finalize BN stats ----------
__global__ void k_stats(const float* __restrict__ sums, float* __restrict__ murs, float invn) {
    int f = threadIdx.x;
    if (f < DD) {
        float mu = sums[f] * invn;
        float var = sums[DD + f] * invn - mu * mu;
        murs[f] = mu;
        murs[DD + f] = rsqrtf(var + 1e-5f);
    }
}

// ---------- recompute v, BN-apply + relu + residual ----------
__global__ __launch_bounds__(256) void k_apply(const float* __restrict__ hin,
                                               const float* __restrict__ PA,
                                               const float* __restrict__ num,
                                               const float* __restrict__ den,
                                               const float* __restrict__ snn,
                                               const float* __restrict__ murs,
                                               const float* __restrict__ g,
                                               const float* __restrict__ b,
                                               float* __restrict__ hout) {
    long idx = (long)blockIdx.x * 256 + threadIdx.x;
    if (idx < (long)NN * DD) {
        int i = (int)(idx / DD);
        int f = (int)(idx - (long)i * DD);
        float v = (PA[idx] + num[idx] / (den[idx] + 1e-6f)) * snn[i];
        float bnv = (v - murs[f]) * murs[DD + f] * g[f] + b[f];
        hout[idx] = hin[idx] + fmaxf(bnv, 0.f);
    }
}

// ---------- per-graph sums (ids sorted -> run-length within block) ----------
__global__ __launch_bounds__(640) void k_readout(const float* __restrict__ h,
                                                 const int* __restrict__ gid,
                                                 float* __restrict__ gsum,
                                                 float* __restrict__ gcnt) {
    __shared__ float sv[9 * DD];
    __shared__ int sg_[9];
    int t = threadIdx.x;
    int r = t / DD, f = t - r * DD;
    int i = blockIdx.x * 9 + r;
    if (r < 9 && i < NN) {
        sv[r * DD + f] = h[(long)i * DD + f];
        if (f == 0) sg_[r] = gid[i];
    }
    __syncthreads();
    int nvalid = NN - blockIdx.x * 9;
    if (nvalid > 9) nvalid = 9;
    if (t < DD && nvalid > 0) {
        float acc = 0.f;
        int cur = sg_[0];
        for (int rr = 0; rr < nvalid; ++rr) {
            int g = sg_[rr];
            if (g != cur) {
                unsafeAtomicAdd(&gsum[cur * DD + t], acc);
                acc = 0.f;
                cur = g;
            }
            acc += sv[rr * DD + t];
        }
        unsafeAtomicAdd(&gsum[cur * DD + t], acc);
        if (t == 0) {
            int cnt = 0;
            cur = sg_[0];
            for (int rr = 0; rr < nvalid; ++rr) {
                if (sg_[rr] != cur) {
                    unsafeAtomicAdd(&gcnt[cur], (float)cnt);
                    cnt = 0;
                    cur = sg_[rr];
                }
                cnt++;
            }
            unsafeAtomicAdd(&gcnt[cur], (float)cnt);
        }
    }
}

__global__ void k_out(const float* __restrict__ gsum, const float* __restrict__ gcnt,
                      float* __restrict__ out) {
    int idx = blockIdx.x * 256 + threadIdx.x;
    if (idx < NG * DD) {
        int g = idx / DD;
        out[idx] = gsum[idx] / fmaxf(gcnt[g], 1.f);
    }
}

extern "C" void kernel_launch(void* const* d_in, const int* in_sizes, int n_in,
                              void* d_out, int out_size, void* d_ws, size_t ws_size,
                              hipStream_t stream) {
    const float* x   = (const float*)d_in[0];
    const float* ef  = (const float*)d_in[1];
    const float* snn = (const float*)d_in[2];
    const float* sne = (const float*)d_in[3];
    const int*   src = (const int*)d_in[4];
    const int*   dst = (const int*)d_in[5];
    const int*   gid = (const int*)d_in[6];
    const float* Wh  = (const float*)d_in[7];
    const float* bh  = (const float*)d_in[8];
    const float* We  = (const float*)d_in[9];
    const float* be  = (const float*)d_in[10];
    const float* Wg  = (const float*)d_in[11];
    const float* bg  = (const float*)d_in[12];
    const float* gh  = (const float*)d_in[13];
    const float* bbh = (const float*)d_in[14];
    const float* ge  = (const float*)d_in[15];
    const float* bbe = (const float*)d_in[16];
    float* out = (float*)d_out;

    const size_t NF = (size_t)NN * DD;  // 7,000,000

    float* ws = (float*)d_ws;
    float* B0 = ws;            // h0 -> PD2 -> h_final
    float* B1 = B0 + NF;       // h1
    float* B2 = B1 + NF;       // PA / PA2
    float* B3 = B2 + NF;       // PB / PB2
    float* B4 = B3 + NF;       // PD0 (kept through k_edge2)
    float* B5 = B4 + NF;       // PE0 (kept through k_edge2)
    float* B6 = B5 + NF;       // PE2
    float* num = B6 + NF;      // NF
    float* den = num + NF;     // NF
    float* red  = den + NF;        // 4*DD
    float* gsum = red + 4 * DD;    // NG*DD
    float* gcnt = gsum + NG * DD;  // NG
    float* v1 = gcnt + NG;
    float* v2 = v1 + DD;
    float* murs_e = v2 + DD;       // 2*DD
    float* murs_h = murs_e + 2 * DD;
    int* off   = (int*)(murs_h + 2 * DD);  // NN (counts -> offsets -> shifted ends)
    int* part  = off + NN;                  // 256
    int* src_s = part + 256;                // NE
    float* ef_s  = (float*)(src_s + NE);    // NE
    float* sne_s = ef_s + NE;               // NE

    size_t need = (size_t)((char*)(sne_s + NE) - (char*)d_ws);  // ~264.4 MB
    if (ws_size < need) return;

    const int NB_N36 = (NN + 35) / 36;        // 2778
    const int NB_N9  = (NN + 8) / 9;          // 11112
    const int NB_E256 = (NE + 255) / 256;     // 3907
    const int NB_SC  = (NN + SCB - 1) / SCB;  // 196
    const int NB_E0  = ((NN + NPS - 1) / NPS + 8) / 9;  // 3705 blocks (9 slots x NPS nodes)
    const int NB_E2  = (NE + CHUNK - 1) / CHUNK;        // 2021 blocks

    // zero: stats/readout accumulators + CSR counts
    hipMemsetAsync(red, 0, (4 * DD + NG * DD + NG) * sizeof(float), stream);
    hipMemsetAsync(off, 0, NN * sizeof(int), stream);

    // ---- CSR build (dst-sorted edge arrays) ----
    k_count<<<NB_E256, 256, 0, stream>>>(dst, off);
    k_scan_a<<<NB_SC, SCB, 0, stream>>>(off, part);
    k_scan_b<<<1, 256, 0, stream>>>(part, NB_SC);
    k_scan_c<<<NB_SC, SCB, 0, stream>>>(off, part);
    k_fill<<<NB_E256, 256, 0, stream>>>(src, dst, ef, sne, off, src_s, ef_s, sne_s);

    k_pre<<<1, 128, 0, stream>>>(We, be, Wg, bg, v1, v2);
    k_dense<64><<<NB_N36, 640, 0, stream>>>(x, Wh, bh, B0, NN);

    // ---- layer 0 (params index 0) ----
    k_dense<70><<<NB_N36, 640, 0, stream>>>(B0, Wg + 0 * 4900, bg + 0 * 70, B2, NN);  // A
    k_dense<70><<<NB_N36, 640, 0, stream>>>(B0, Wg + 1 * 4900, bg + 1 * 70, B3, NN);  // B
    k_dense<70><<<NB_N36, 640, 0, stream>>>(B0, Wg + 3 * 4900, bg + 3 * 70, B4, NN);  // D
    k_dense<70><<<NB_N36, 640, 0, stream>>>(B0, Wg + 4 * 4900, bg + 4 * 70, B5, NN);  // E
    k_edge0<<<NB_E0, 640, 0, stream>>>(ef_s, sne_s, src_s, off, B3, B4, B5, v1, v2,
                                       num, den, red);
    k_stats<<<1, 128, 0, stream>>>(red, murs_e, 1.f / NE);
    k_nstats<<<2048, 640, 0, stream>>>(B2, num, den, snn, red + 2 * DD);
    k_stats<<<1, 128, 0, stream>>>(red + 2 * DD, murs_h, 1.f / NN);
    k_apply<<<(int)((NF + 255) / 256), 256, 0, stream>>>(B0, B2, num, den, snn, murs_h,
                                                         gh + 0, bbh + 0, B1);

    // ---- layer 2 (params index 2) ----
    hipMemsetAsync(num, 0, (2 * NF + 4 * DD) * sizeof(float), stream);  // num, den, red
    k_dense<70><<<NB_N36, 640, 0, stream>>>(B1, Wg + 10 * 4900, bg + 10 * 70, B2, NN); // A
    k_dense<70><<<NB_N36, 640, 0, stream>>>(B1, Wg + 11 * 4900, bg + 11 * 70, B3, NN); // B
    k_dense<70><<<NB_N36, 640, 0, stream>>>(B1, Wg + 13 * 4900, bg + 13 * 70, B0, NN); // D
    k_dense<70><<<NB_N36, 640, 0, stream>>>(B1, Wg + 14 * 4900, bg + 14 * 70, B6, NN); // E
    k_edge2<<<NB_E2, 640, 0, stream>>>(ef_s, sne_s, src_s, off, B4, B5, B3, B0, B6,
                                       v1, v2, murs_e, ge + 0, bbe + 0, We, be,
                                       Wg + 12 * 4900, bg + 12 * 70, num, den);
    k_nstats<<<2048, 640, 0, stream>>>(B2, num, den, snn, red + 2 * DD);
    k_stats<<<1, 128, 0, stream>>>(red + 2 * DD, murs_h, 1.f / NN);
    k_apply<<<(int)((NF + 255) / 256), 256, 0, stream>>>(B1, B2, num, den, snn, murs_h,
                                                         gh + 2 * DD, bbh + 2 * DD, B0);

    // ---- readout ----
    k_readout<<<NB_N9, 640, 0, stream>>>(B0, gid, gsum, gcnt);
    k_out<<<(NG * DD + 255) / 256, 256, 0, stream>>>(gsum, gcnt, out);
}

// Round 7
// 2141.861 us; speedup vs baseline: 1.0167x; 1.0167x over previous
//
#include <hip/hip_runtime.h>

#define NN 100000
#define NE 1000000
#define NG 100
#define DD 70
#define EL 55              // edges per slot in k_edge2
#define CHUNK (9 * EL)     // 495 edges per block
#define NPS 3              // nodes per slot in k_edge0
#define SCB 512
#define WTS (70 * 72)      // one transposed weight matrix, padded

__device__ __forceinline__ float sigmoidf_(float x) { return 1.f / (1.f + expf(-x)); }

// 18 named float4 weight registers + FMA helpers (no arrays -> guaranteed promotion)
#define LDW(i) const float4 W##i = wrow[i];
#define LDW_ALL LDW(0) LDW(1) LDW(2) LDW(3) LDW(4) LDW(5) LDW(6) LDW(7) LDW(8) \
                LDW(9) LDW(10) LDW(11) LDW(12) LDW(13) LDW(14) LDW(15) LDW(16) LDW(17)
#define FMA4(i) { float4 v_ = xr[i]; acc = fmaf(v_.x, W##i.x, acc); acc = fmaf(v_.y, W##i.y, acc); \
                  acc = fmaf(v_.z, W##i.z, acc); acc = fmaf(v_.w, W##i.w, acc); }
#define FMA4_ALL FMA4(0) FMA4(1) FMA4(2) FMA4(3) FMA4(4) FMA4(5) FMA4(6) FMA4(7) FMA4(8) \
                 FMA4(9) FMA4(10) FMA4(11) FMA4(12) FMA4(13) FMA4(14) FMA4(15) FMA4(16) FMA4(17)

// ---------- transpose all 10 weight matrices into WT[m][70][72], zero-padded ----------
__global__ void k_trAll(const float* __restrict__ Wh, const float* __restrict__ Wg,
                        float* __restrict__ WT) {
    int m = blockIdx.y, f = blockIdx.x, k = threadIdx.x;  // k in [0,72)
    const float* W;
    int K = DD;
    switch (m) {
        case 0: W = Wh; K = 64; break;
        case 1: W = Wg + 0 * 4900; break;
        case 2: W = Wg + 1 * 4900; break;
        case 3: W = Wg + 3 * 4900; break;
        case 4: W = Wg + 4 * 4900; break;
        case 5: W = Wg + 10 * 4900; break;
        case 6: W = Wg + 11 * 4900; break;
        case 7: W = Wg + 13 * 4900; break;
        case 8: W = Wg + 14 * 4900; break;
        default: W = Wg + 12 * 4900; break;  // m=9: C2
    }
    if (k < 72) WT[(m * 70 + f) * 72 + k] = (k < K) ? W[k * DD + f] : 0.f;
}

// ---------- skinny dense with register-resident weight column ----------
__global__ __launch_bounds__(640) void k_dense_r(const float* __restrict__ x, int K,
                                                 const float* __restrict__ WTm,
                                                 const float* __restrict__ bias,
                                                 float* __restrict__ out, int nrows) {
    __shared__ float sx[9 * 72];
    int t = threadIdx.x;
    int r = t / DD, f = t - r * DD;
    const float4* wrow = (const float4*)(WTm + f * 72);
    LDW_ALL
    float bb = bias[f];
    for (int idx = t; idx < 9 * 72; idx += 640) sx[idx] = 0.f;
    __syncthreads();
    int base = blockIdx.x * 36;
    for (int c = 0; c < 4; ++c) {
        int rb = base + c * 9;
        for (int idx = t; idx < 9 * K; idx += 640) {
            int rr = idx / K, kk = idx - rr * K;
            int i = rb + rr;
            sx[rr * 72 + kk] = (i < nrows) ? x[(long)i * K + kk] : 0.f;
        }
        __syncthreads();
        int i = rb + r;
        if (r < 9 && i < nrows) {
            float acc = bb;
            const float4* xr = (const float4*)&sx[r * 72];
            FMA4_ALL
            out[(long)i * DD + f] = acc;
        }
        __syncthreads();
    }
}

// ---------- v1 = We @ Wc0 ; v2 = be @ Wc0 + bc0 ----------
__global__ void k_pre(const float* __restrict__ We, const float* __restrict__ be,
                      const float* __restrict__ Wg, const float* __restrict__ bg,
                      float* __restrict__ v1, float* __restrict__ v2) {
    int f = threadIdx.x;
    if (f < DD) {
        const float* W2 = Wg + 2 * DD * DD;  // layer0, proj C
        const float* b2 = bg + 2 * DD;
        float a = 0.f, c = 0.f;
        for (int k = 0; k < DD; ++k) {
            a = fmaf(We[k], W2[k * DD + f], a);
            c = fmaf(be[k], W2[k * DD + f], c);
        }
        v1[f] = a;
        v2[f] = c + b2[f];
    }
}

// ---------- CSR build: count / scan / fill ----------
__global__ void k_count(const int* __restrict__ dst, int* __restrict__ off) {
    int j = blockIdx.x * 256 + threadIdx.x;
    if (j < NE) atomicAdd(&off[dst[j]], 1);
}

__global__ void k_scan_a(int* __restrict__ off, int* __restrict__ part) {
    __shared__ int s[SCB];
    int t = threadIdx.x, i = blockIdx.x * SCB + t;
    int v = (i < NN) ? off[i] : 0;
    s[t] = v;
    __syncthreads();
    for (int d = 1; d < SCB; d <<= 1) {
        int x = (t >= d) ? s[t - d] : 0;
        __syncthreads();
        s[t] += x;
        __syncthreads();
    }
    if (i < NN) off[i] = s[t] - v;
    if (t == SCB - 1) part[blockIdx.x] = s[t];
}

__global__ void k_scan_b(int* __restrict__ part, int nb) {
    __shared__ int s[256];
    int t = threadIdx.x;
    int v = (t < nb) ? part[t] : 0;
    s[t] = v;
    __syncthreads();
    for (int d = 1; d < 256; d <<= 1) {
        int x = (t >= d) ? s[t - d] : 0;
        __syncthreads();
        s[t] += x;
        __syncthreads();
    }
    if (t < nb) part[t] = s[t] - v;
}

__global__ void k_scan_c(int* __restrict__ off, const int* __restrict__ part) {
    int i = blockIdx.x * SCB + threadIdx.x;
    if (i < NN) off[i] += part[blockIdx.x];
}

__global__ void k_fill(const int* __restrict__ src, const int* __restrict__ dst,
                       const float* __restrict__ ef, const float* __restrict__ sne,
                       int* __restrict__ off, int* __restrict__ src_s,
                       float* __restrict__ ef_s, float* __restrict__ sne_s) {
    int j = blockIdx.x * 256 + threadIdx.x;
    if (j < NE) {
        int d = dst[j];
        int pos = atomicAdd(&off[d], 1);  // off becomes shifted: off[n] = end(n)
        src_s[pos] = src[j];
        ef_s[pos] = ef[j];
        sne_s[pos] = sne[j];
    }
}

// ---------- layer-0 edge pass: node-centric, ZERO global atomics ----------
__global__ __launch_bounds__(640) void k_edge0(
    const float* __restrict__ ef_s, const float* __restrict__ sne_s,
    const int* __restrict__ src_s, const int* __restrict__ off,
    const float* __restrict__ PB, const float* __restrict__ PD,
    const float* __restrict__ PE, const float* __restrict__ v1,
    const float* __restrict__ v2, float* __restrict__ num,
    float* __restrict__ den, float* __restrict__ red) {
    int t = threadIdx.x;
    int r = t / DD, f = t - r * DD;
    bool act = (r < 9);
    float c1 = 0.f, c2 = 0.f;
    if (act) { c1 = v1[f]; c2 = v2[f]; }
    float acc_s = 0.f, acc_q = 0.f;
    int sid = blockIdx.x * 9 + r;
    int n0 = sid * NPS, n1 = n0 + NPS;
    if (n1 > NN) n1 = NN;
    if (act && n0 < NN) {
        int e = (n0 == 0) ? 0 : off[n0 - 1];
        for (int nn = n0; nn < n1; ++nn) {
            int e_end = off[nn];
            float pe = PE[(long)nn * DD + f];
            float na = 0.f, da = 0.f;
            for (; e < e_end; ++e) {
                int s = src_s[e];
                float efv = ef_s[e], snv = sne_s[e];
                float en = PD[(long)s * DD + f] + pe + efv * c1 + c2;
                float sg = sigmoidf_(en);
                na = fmaf(sg, PB[(long)s * DD + f], na);
                da += sg;
                float tv = en * snv;
                acc_s += tv;
                acc_q = fmaf(tv, tv, acc_q);
            }
            num[(long)nn * DD + f] = na;
            den[(long)nn * DD + f] = da;
        }
    }
    __shared__ float ss[DD], sq[DD];
    if (t < DD) { ss[t] = 0.f; sq[t] = 0.f; }
    __syncthreads();
    if (act) { atomicAdd(&ss[f], acc_s); atomicAdd(&sq[f], acc_q); }
    __syncthreads();
    if (t < DD) {
        atomicAdd(&red[t], ss[t]);
        atomicAdd(&red[DD + t], sq[t]);
    }
}

// ---------- layer-2 edge kernel: sorted edges, weights in named float4 registers ----------
__global__ __launch_bounds__(640, 2) void k_edge2(
    const float* __restrict__ ef_s, const float* __restrict__ sne_s,
    const int* __restrict__ src_s, const int* __restrict__ off,
    const float* __restrict__ PD0, const float* __restrict__ PE0,
    const float* __restrict__ PB2, const float* __restrict__ PD2,
    const float* __restrict__ PE2,
    const float* __restrict__ v1, const float* __restrict__ v2,
    const float* __restrict__ murs_e, const float* __restrict__ ge,
    const float* __restrict__ bbe, const float* __restrict__ We,
    const float* __restrict__ be,
    const float* __restrict__ WT9, const float* __restrict__ bC2,
    float* __restrict__ num, float* __restrict__ den) {
    __shared__ float se[9 * 72];  // padded rows, 16B-aligned; pads zeroed once
    int t = threadIdx.x;
    int r = t / DD, f = t - r * DD;
    bool act = (r < 9);
    const float4* wrow = (const float4*)(WT9 + f * 72);
    LDW_ALL
    float c_v1 = 0.f, c_v2 = 0.f, c_mu = 0.f, c_rs = 0.f, c_g = 0.f, c_b = 0.f,
          c_We = 0.f, c_be = 0.f, c_b2 = 0.f;
    if (act) {
        c_v1 = v1[f]; c_v2 = v2[f];
        c_mu = murs_e[f]; c_rs = murs_e[DD + f];
        c_g = ge[f]; c_b = bbe[f];
        c_We = We[f]; c_be = be[f];
        c_b2 = bC2[f];
    }
    for (int idx = t; idx < 9 * 72; idx += 640) se[idx] = 0.f;
    int e_beg = blockIdx.x * CHUNK + r * EL;
    bool live = act && e_beg < NE;
    int n = 0;
    float pe0 = 0.f, pe2 = 0.f, accn = 0.f, accd = 0.f;
    if (live) {
        int lo = 0, hi = NN - 1;  // smallest n with off[n] > e_beg (off[n] = end(n))
        while (lo < hi) {
            int mid = (lo + hi) >> 1;
            if (off[mid] > e_beg) hi = mid; else lo = mid + 1;
        }
        n = lo;
        pe0 = PE0[(long)n * DD + f];
        pe2 = PE2[(long)n * DD + f];
    }
    __syncthreads();  // zeros visible before first stage
    int s = 0;
    for (int it = 0; it < EL; ++it) {
        int e = e_beg + it;
        bool ok = live && e < NE;
        if (ok) {
            if (e >= off[n]) {  // crossed into next dst run: flush
                unsafeAtomicAdd(&num[(long)n * DD + f], accn);
                unsafeAtomicAdd(&den[(long)n * DD + f], accd);
                accn = 0.f; accd = 0.f;
                do { ++n; } while (off[n] <= e);  // skip empty buckets
                pe0 = PE0[(long)n * DD + f];
                pe2 = PE2[(long)n * DD + f];
            }
            s = src_s[e];
            float efv = ef_s[e], snv = sne_s[e];
            // e1[e,f] = e0 + relu(bn_e((Dh0[s]+Eh0[d]+Ce0)*sne))
            float en0 = PD0[(long)s * DD + f] + pe0 + efv * c_v1 + c_v2;
            float tv = en0 * snv;
            float bnv = (tv - c_mu) * c_rs * c_g + c_b;
            float e0v = fmaf(efv, c_We, c_be);
            se[r * 72 + f] = e0v + fmaxf(bnv, 0.f);
        }
        __syncthreads();
        if (ok) {
            float acc = c_b2;
            const float4* xr = (const float4*)&se[r * 72];
            FMA4_ALL
            float en = PD2[(long)s * DD + f] + pe2 + acc;
            float sg = sigmoidf_(en);
            accn = fmaf(sg, PB2[(long)s * DD + f], accn);
            accd += sg;
        }
        __syncthreads();
    }
    if (live) {
        unsafeAtomicAdd(&num[(long)n * DD + f], accn);
        unsafeAtomicAdd(&den[(long)n * DD + f], accd);
    }
}

// ---------- node BN stats: grid-stride, reg-accum ----------
__global__ __launch_bounds__(640) void k_nstats(const float* __restrict__ PA,
                                                const float* __restrict__ num,
                                                const float* __restrict__ den,
                                                const float* __restrict__ snn,
                                                float* __restrict__ red) {
    int t = threadIdx.x;
    int r = t / DD, f = t - r * DD;
    bool act = (r < 9);
    float acc_s = 0.f, acc_q = 0.f;
    const int T = (NN + 8) / 9;
    for (int tile = blockIdx.x; tile < T; tile += gridDim.x) {
        int i = tile * 9 + r;
        if (act && i < NN) {
            long o = (long)i * DD + f;
            float v = (PA[o] + num[o] / (den[o] + 1e-6f)) * snn[i];
            acc_s += v;
            acc_q = fmaf(v, v, acc_q);
        }
    }
    __shared__ float ss[DD], sq[DD];
    if (t < DD) { ss[t] = 0.f; sq[t] = 0.f; }
    __syncthreads();
    if (act) { atomicAdd(&ss[f], acc_s); atomicAdd(&sq[f], acc_q); }
    __syncthreads();
    if (t < DD) {
        atomicAdd(&red[t], ss[t]);
        atomicAdd(&red[DD + t], sq[t]);
    }
}

// ---------- finalize BN stats ----------
__global__ void k_stats(const float* __restrict__ sums, float* __restrict__ murs, float invn) {
    int f = threadIdx.x;
    if (f < DD) {
        float mu = sums[f] * invn;
        float var = sums[DD + f] * invn - mu * mu;
        murs[f] = mu;
        murs[DD + f] = rsqrtf(var + 1e-5f);
    }
}

// ---------- recompute v, BN-apply + relu + residual ----------
__global__ __launch_bounds__(256) void k_apply(const float* __restrict__ hin,
                                               const float* __restrict__ PA,
                                               const float* __restrict__ num,
                                               const float* __restrict__ den,
                                               const float* __restrict__ snn,
                                               const float* __restrict__ murs,
                                               const float* __restrict__ g,
                                               const float* __restrict__ b,
                                               float* __restrict__ hout) {
    long idx = (long)blockIdx.x * 256 + threadIdx.x;
    if (idx < (long)NN * DD) {
        int i = (int)(idx / DD);
        int f = (int)(idx - (long)i * DD);
        float v = (PA[idx] + num[idx] / (den[idx] + 1e-6f)) * snn[i];
        float bnv = (v - murs[f]) * murs[DD + f] * g[f] + b[f];
        hout[idx] = hin[idx] + fmaxf(bnv, 0.f);
    }
}

// ---------- per-graph sums (ids sorted -> run-length within block) ----------
__global__ __launch_bounds__(640) void k_readout(const float* __restrict__ h,
                                                 const int* __restrict__ gid,
                                                 float* __restrict__ gsum,
                                                 float* __restrict__ gcnt) {
    __shared__ float sv[9 * DD];
    __shared__ int sg_[9];
    int t = threadIdx.x;
    int r = t / DD, f = t - r * DD;
    int i = blockIdx.x * 9 + r;
    if (r < 9 && i < NN) {
        sv[r * DD + f] = h[(long)i * DD + f];
        if (f == 0) sg_[r] = gid[i];
    }
    __syncthreads();
    int nvalid = NN - blockIdx.x * 9;
    if (nvalid > 9) nvalid = 9;
    if (t < DD && nvalid > 0) {
        float acc = 0.f;
        int cur = sg_[0];
        for (int rr = 0; rr < nvalid; ++rr) {
            int g = sg_[rr];
            if (g != cur) {
                unsafeAtomicAdd(&gsum[cur * DD + t], acc);
                acc = 0.f;
                cur = g;
            }
            acc += sv[rr * DD + t];
        }
        unsafeAtomicAdd(&gsum[cur * DD + t], acc);
        if (t == 0) {
            int cnt = 0;
            cur = sg_[0];
            for (int rr = 0; rr < nvalid; ++rr) {
                if (sg_[rr] != cur) {
                    unsafeAtomicAdd(&gcnt[cur], (float)cnt);
                    cnt = 0;
                    cur = sg_[rr];
                }
                cnt++;
            }
            unsafeAtomicAdd(&gcnt[cur], (float)cnt);
        }
    }
}

__global__ void k_out(const float* __restrict__ gsum, const float* __restrict__ gcnt,
                      float* __restrict__ out) {
    int idx = blockIdx.x * 256 + threadIdx.x;
    if (idx < NG * DD) {
        int g = idx / DD;
        out[idx] = gsum[idx] / fmaxf(gcnt[g], 1.f);
    }
}

extern "C" void kernel_launch(void* const* d_in, const int* in_sizes, int n_in,
                              void* d_out, int out_size, void* d_ws, size_t ws_size,
                              hipStream_t stream) {
    const float* x   = (const float*)d_in[0];
    const float* ef  = (const float*)d_in[1];
    const float* snn = (const float*)d_in[2];
    const float* sne = (const float*)d_in[3];
    const int*   src = (const int*)d_in[4];
    const int*   dst = (const int*)d_in[5];
    const int*   gid = (const int*)d_in[6];
    const float* Wh  = (const float*)d_in[7];
    const float* bh  = (const float*)d_in[8];
    const float* We  = (const float*)d_in[9];
    const float* be  = (const float*)d_in[10];
    const float* Wg  = (const float*)d_in[11];
    const float* bg  = (const float*)d_in[12];
    const float* gh  = (const float*)d_in[13];
    const float* bbh = (const float*)d_in[14];
    const float* ge  = (const float*)d_in[15];
    const float* bbe = (const float*)d_in[16];
    float* out = (float*)d_out;

    const size_t NF = (size_t)NN * DD;  // 7,000,000

    float* ws = (float*)d_ws;
    float* B0 = ws;            // h0 -> PD2 -> h_final
    float* B1 = B0 + NF;       // h1
    float* B2 = B1 + NF;       // PA / PA2
    float* B3 = B2 + NF;       // PB / PB2
    float* B4 = B3 + NF;       // PD0 (kept through k_edge2)
    float* B5 = B4 + NF;       // PE0 (kept through k_edge2)
    float* B6 = B5 + NF;       // PE2
    float* num = B6 + NF;      // NF
    float* den = num + NF;     // NF
    float* red  = den + NF;        // 4*DD
    float* gsum = red + 4 * DD;    // NG*DD
    float* gcnt = gsum + NG * DD;  // NG
    float* v1 = gcnt + NG;
    float* v2 = v1 + DD;
    float* murs_e = v2 + DD;       // 2*DD
    float* murs_h = murs_e + 2 * DD;
    int* off   = (int*)(murs_h + 2 * DD);  // NN
    int* part  = off + NN;                  // 256
    int* src_s = part + 256;                // NE
    float* ef_s  = (float*)(src_s + NE);    // NE
    float* sne_s = ef_s + NE;               // NE
    float* WT    = sne_s + NE;              // 10 * WTS  (transposed, padded weights)

    size_t need = (size_t)((char*)(WT + 10 * WTS) - (char*)d_ws);  // ~264.6 MB
    if (ws_size < need) return;

    const int NB_N36 = (NN + 35) / 36;        // 2778
    const int NB_N9  = (NN + 8) / 9;          // 11112
    const int NB_E256 = (NE + 255) / 256;     // 3907
    const int NB_SC  = (NN + SCB - 1) / SCB;  // 196
    const int NB_E0  = ((NN + NPS - 1) / NPS + 8) / 9;  // 3705
    const int NB_E2  = (NE + CHUNK - 1) / CHUNK;        // 2021

    // zero: stats/readout accumulators + CSR counts
    hipMemsetAsync(red, 0, (4 * DD + NG * DD + NG) * sizeof(float), stream);
    hipMemsetAsync(off, 0, NN * sizeof(int), stream);

    // ---- weight transposes + CSR build ----
    k_trAll<<<dim3(70, 10), 72, 0, stream>>>(Wh, Wg, WT);
    k_count<<<NB_E256, 256, 0, stream>>>(dst, off);
    k_scan_a<<<NB_SC, SCB, 0, stream>>>(off, part);
    k_scan_b<<<1, 256, 0, stream>>>(part, NB_SC);
    k_scan_c<<<NB_SC, SCB, 0, stream>>>(off, part);
    k_fill<<<NB_E256, 256, 0, stream>>>(src, dst, ef, sne, off, src_s, ef_s, sne_s);

    k_pre<<<1, 128, 0, stream>>>(We, be, Wg, bg, v1, v2);
    k_dense_r<<<NB_N36, 640, 0, stream>>>(x, 64, WT + 0 * WTS, bh, B0, NN);

    // ---- layer 0 (params index 0) ----
    k_dense_r<<<NB_N36, 640, 0, stream>>>(B0, 70, WT + 1 * WTS, bg + 0 * 70, B2, NN);  // A
    k_dense_r<<<NB_N36, 640, 0, stream>>>(B0, 70, WT + 2 * WTS, bg + 1 * 70, B3, NN);  // B
    k_dense_r<<<NB_N36, 640, 0, stream>>>(B0, 70, WT + 3 * WTS, bg + 3 * 70, B4, NN);  // D
    k_dense_r<<<NB_N36, 640, 0, stream>>>(B0, 70, WT + 4 * WTS, bg + 4 * 70, B5, NN);  // E
    k_edge0<<<NB_E0, 640, 0, stream>>>(ef_s, sne_s, src_s, off, B3, B4, B5, v1, v2,
                                       num, den, red);
    k_stats<<<1, 128, 0, stream>>>(red, murs_e, 1.f / NE);
    k_nstats<<<2048, 640, 0, stream>>>(B2, num, den, snn, red + 2 * DD);
    k_stats<<<1, 128, 0, stream>>>(red + 2 * DD, murs_h, 1.f / NN);
    k_apply<<<(int)((NF + 255) / 256), 256, 0, stream>>>(B0, B2, num, den, snn, murs_h,
                                                         gh + 0, bbh + 0, B1);

    // ---- layer 2 (params index 2) ----
    hipMemsetAsync(num, 0, (2 * NF + 4 * DD) * sizeof(float), stream);  // num, den, red
    k_dense_r<<<NB_N36, 640, 0, stream>>>(B1, 70, WT + 5 * WTS, bg + 10 * 70, B2, NN); // A
    k_dense_r<<<NB_N36, 640, 0, stream>>>(B1, 70, WT + 6 * WTS, bg + 11 * 70, B3, NN); // B
    k_dense_r<<<NB_N36, 640, 0, stream>>>(B1, 70, WT + 7 * WTS, bg + 13 * 70, B0, NN); // D
    k_dense_r<<<NB_N36, 640, 0, stream>>>(B1, 70, WT + 8 * WTS, bg + 14 * 70, B6, NN); // E
    k_edge2<<<NB_E2, 640, 0, stream>>>(ef_s, sne_s, src_s, off, B4, B5, B3, B0, B6,
                                       v1, v2, murs_e, ge + 0, bbe + 0, We, be,
                                       WT + 9 * WTS, bg + 12 * 70, num, den);
    k_nstats<<<2048, 640, 0, stream>>>(B2, num, den, snn, red + 2 * DD);
    k_stats<<<1, 128, 0, stream>>>(red + 2 * DD, murs_h, 1.f / NN);
    k_apply<<<(int)((NF + 255) / 256), 256, 0, stream>>>(B1, B2, num, den, snn, murs_h,
                                                         gh + 2 * DD, bbh + 2 * DD, B0);

    // ---- readout ----
    k_readout<<<NB_N9, 640, 0, stream>>>(B0, gid, gsum, gcnt);
    k_out<<<(NG * DD + 255) / 256, 256, 0, stream>>>(gsum, gcnt, out);
}